// Round 4
// baseline (1010.007 us; speedup 1.0000x reference)
//
#include <hip/hip_runtime.h>
#include <hip/hip_bf16.h>
#include <cstddef>

#define NB 32
#define CC 64
#define TT 16
#define VV 256
#define KK 5

typedef __attribute__((ext_vector_type(8))) short short8;
typedef __attribute__((ext_vector_type(4))) float f32x4;

union U16B { short8 s8; uint2 u2[2]; uint4 u4; unsigned u[4]; unsigned short us[8]; };

__device__ inline unsigned short f2bf(float f) {
    unsigned u = __float_as_uint(f);
    return (unsigned short)((u + 0x7fffu + ((u >> 16) & 1u)) >> 16);
}
// packed bf16 convert (RNE, same rounding as f2bf): low = a, high = b
__device__ inline unsigned cvtpk(float a, float b) {
    unsigned r;
    asm("v_cvt_pk_bf16_f32 %0, %1, %2" : "=v"(r) : "v"(a), "v"(b));
    return r;
}

// ---------------------------------------------------------------------------
// K1: pure vectorized copy A -> out tail (degree sums computed in k_fuse).
__global__ __launch_bounds__(256) void k_copyA(const float4* __restrict__ A4,
                                               float4* __restrict__ outA4)
{
    int n = blockIdx.x, rb = blockIdx.y, t = threadIdx.x;
    size_t base = (size_t)n * (KK * VV * VV / 4) + (size_t)rb * (32 * 64)
                + (size_t)(t >> 6) * (8 * 64) + (t & 63);
#pragma unroll
    for (int i = 0; i < 8; i++)
        outA4[base + i * 64] = A4[base + i * 64];
}

// ---------------------------------------------------------------------------
// K2: xcb[n,c,t,v] = bf16( sum_ci Wc[c,ci]*x[n,ci,t,v] + bc[c] )
__global__ __launch_bounds__(256) void k_xc(const float* __restrict__ x,
                                            const float* __restrict__ Wc,
                                            const float* __restrict__ bc,
                                            __hip_bfloat16* __restrict__ xcb)
{
    __shared__ float WT[64 * 64];  // WT[ci][co]
    __shared__ float bs[64];
    int n = blockIdx.x, tid = threadIdx.x;
    int p = blockIdx.y * 256 + tid;  // t*256+v index
    for (int i = tid; i < 4096; i += 256) WT[(i & 63) * 64 + (i >> 6)] = Wc[i];
    if (tid < 64) bs[tid] = bc[tid];
    __syncthreads();

    float acc[64];
#pragma unroll
    for (int c = 0; c < 64; c++) acc[c] = bs[c];
#pragma unroll 4
    for (int ci = 0; ci < 64; ci++) {
        float xv = x[((size_t)n * 64 + ci) * 4096 + p];
        const float4* wr = (const float4*)&WT[ci * 64];
#pragma unroll
        for (int q = 0; q < 16; q++) {
            float4 w4 = wr[q];
            acc[q * 4 + 0] = fmaf(w4.x, xv, acc[q * 4 + 0]);
            acc[q * 4 + 1] = fmaf(w4.y, xv, acc[q * 4 + 1]);
            acc[q * 4 + 2] = fmaf(w4.z, xv, acc[q * 4 + 2]);
            acc[q * 4 + 3] = fmaf(w4.w, xv, acc[q * 4 + 3]);
        }
    }
#pragma unroll
    for (int c = 0; c < 64; c++)
        xcb[((size_t)n * 64 + c) * 4096 + p] = __float2bfloat16(acc[c]);
}

// ---------------------------------------------------------------------------
// K3 fused v4: pingpong Ms double-buffer, ONE barrier per vc.
//  iteration vc: [PhaseB(vc) from Ms[vc&1]  ||  PhaseA(vc+1) -> Ms[(vc+1)&1]]
//                -> __syncthreads()
// xcb fragments for vc+1 are register-prefetched (two named arrays, static idx).
// LDS layout:
//  [0,16)  zero block
//  h1: per wave 64 rows x 32B, pair-XOR swizzle     (2048 / wave)
//  h2: per wave 64 rows x 72B (verified layout)     (4608 / wave)
//  Ms: 2 buffers x 64 ch x 34 units x 16B           (34816 each)
//      unit count per channel EVEN -> u^=1 swizzle stays in-block (bijective).
#define H1SZ 2048
#define H2RS 72
#define HWAVE (H1SZ + 64 * H2RS)           // 6656
#define MS_UST 34                           // 16B units per channel (32 data + 2 pad)
#define MSBUF (64 * MS_UST * 16)            // 34816 bytes
#define LDS_H0 16
#define LDS_MS (LDS_H0 + 4 * HWAVE)         // 26640
#define LDS_TOTAL (LDS_MS + 2 * MSBUF)      // 96272

// h1 byte offset within a wave's h1 region: row in [0,64), 16B-half h in {0,1}
__device__ inline int h1_off(int row, int h) {
    int u = row * 2 + h;
    u ^= (row >> 2) & 1;
    return u * 16;
}
// Ms byte offset: channel C in [0,64), w in [0,16), v3 = (v>>3) in {0,1}
// u = C*34 + w*2 + v3 in [C*34, C*34+32); base even => u^1 stays in-block.
__device__ inline int ms_off(int C, int w, int v3) {
    int u = C * MS_UST + w * 2 + v3;
    u ^= (w >> 2) & 1;
    return u * 16;
}

__global__ __launch_bounds__(256, 1) void k_fuse(
    const float* __restrict__ A, const float* __restrict__ hm,
    const __hip_bfloat16* __restrict__ xcb,
    const float* __restrict__ nh_w1, const float* __restrict__ nh_b1,
    const float* __restrict__ nh_w2, const float* __restrict__ nh_b2,
    const float* __restrict__ nh_w3, const float* __restrict__ nh_b3,
    const float* __restrict__ h_w1, const float* __restrict__ h_b1,
    const float* __restrict__ h_w2, const float* __restrict__ h_b2,
    const float* __restrict__ h_w3, const float* __restrict__ h_b3,
    float* __restrict__ out)
{
    __shared__ char smem[LDS_TOTAL];
    int tid = threadIdx.x, lane = tid & 63, wid = tid >> 6;
    int n = blockIdx.x, wt = blockIdx.y;
    int col = lane & 15, quad = lane >> 4;
    int vl = col;  // Phase A lane role: point (w = wid*4+quad, v-local=vl)

    char* h1b = smem + LDS_H0 + wid * HWAVE;
    char* h2b = h1b + H1SZ;

    if (tid < 4) ((unsigned*)smem)[tid] = 0;  // shared 16B zero block

    int w_lane = wt * 16 + wid * 4 + quad;
    bool flag_lane = hm[n * 256 + w_lane] > 0.5f;

    // group (per-pt) branch flags (wave-uniform)
    bool fg[4];
#pragma unroll
    for (int g = 0; g < 4; g++)
        fg[g] = hm[n * 256 + wt * 16 + wid * 4 + g] > 0.5f;

    // --- weight fragments for BOTH branches (VGPR-resident, loaded once) ---
    U16B w2u_n[2], w2u_h[2], w3u_n[4], w3u_h[4];
    f32x4 b2f_n[2], b2f_h[2];
    float b3c_n[4], b3c_h[4];
#pragma unroll
    for (int ot = 0; ot < 2; ot++) {
#pragma unroll
        for (int j = 0; j < 8; j++) {
            int k = quad * 8 + j;
            w2u_n[ot].us[j] = (k < 16) ? f2bf(nh_w2[(ot * 16 + col) * 16 + k]) : (unsigned short)0;
            w2u_h[ot].us[j] = (k < 16) ? f2bf(h_w2[(ot * 16 + col) * 16 + k]) : (unsigned short)0;
        }
#pragma unroll
        for (int r = 0; r < 4; r++) {
            b2f_n[ot][r] = nh_b2[ot * 16 + quad * 4 + r];
            b2f_h[ot][r] = h_b2[ot * 16 + quad * 4 + r];
        }
    }
#pragma unroll
    for (int ot = 0; ot < 4; ot++) {
#pragma unroll
        for (int j = 0; j < 8; j++) {
            w3u_n[ot].us[j] = f2bf(nh_w3[(ot * 16 + col) * 32 + quad * 8 + j]);
            w3u_h[ot].us[j] = f2bf(h_w3[(ot * 16 + col) * 32 + quad * 8 + j]);
        }
        // L3 swapped-operand output: lane's channel is ot*16+col -> scalar bias
        b3c_n[ot] = nh_b3[ot * 16 + col];
        b3c_h[ot] = h_b3[ot * 16 + col];
    }

    f32x4 acc[16];
#pragma unroll
    for (int i = 0; i < 16; i++) acc[i] = f32x4{0.f, 0.f, 0.f, 0.f};

    float asum = 0.f;  // per-lane partial of sum_{k,v} A[n,k,v,w_lane]
    float a_cur[5];

    __syncthreads();  // zero block visible before any MFMA path reads it

    // prefetch A for vc=0
#pragma unroll
    for (int k = 0; k < 5; k++)
        a_cur[k] = A[(((size_t)n * 5 + k) * 256 + vl) * 256 + w_lane];

    // ---- Phase A for chunk vcc -> Ms[vcc&1] ----
    auto phaseA = [&](int vcc) {
        char* msb = smem + LDS_MS + (vcc & 1) * MSBUF;
        float a[5];
#pragma unroll
        for (int k = 0; k < 5; k++) { a[k] = a_cur[k]; asum += a[k]; }

        if (vcc < 15) {  // prefetch next chunk's A (in flight across this iter)
            int v = (vcc + 1) * 16 + vl;
#pragma unroll
            for (int k = 0; k < 5; k++)
                a_cur[k] = A[(((size_t)n * 5 + k) * 256 + v) * 256 + w_lane];
        }

        float h1s[16];
#pragma unroll
        for (int o = 0; o < 16; o++) {
            float sn = nh_b1[o], sh = h_b1[o];
#pragma unroll
            for (int k = 0; k < 5; k++) {
                sn = fmaf(nh_w1[o * 5 + k], a[k], sn);
                sh = fmaf(h_w1[o * 5 + k], a[k], sh);
            }
            h1s[o] = flag_lane ? fmaxf(sh, 0.f) : fmaxf(sn, 0.f);
        }
        uint4 q0, q1;
        q0.x = cvtpk(h1s[0], h1s[1]);   q0.y = cvtpk(h1s[2], h1s[3]);
        q0.z = cvtpk(h1s[4], h1s[5]);   q0.w = cvtpk(h1s[6], h1s[7]);
        q1.x = cvtpk(h1s[8], h1s[9]);   q1.y = cvtpk(h1s[10], h1s[11]);
        q1.z = cvtpk(h1s[12], h1s[13]); q1.w = cvtpk(h1s[14], h1s[15]);
        *(uint4*)(h1b + h1_off(lane, 0)) = q0;
        *(uint4*)(h1b + h1_off(lane, 1)) = q1;

#pragma unroll
        for (int pt = 0; pt < 4; pt++) {
            int row = pt * 16 + col;
            U16B af1;
            {
                const char* p1 = (quad < 2) ? (h1b + h1_off(row, quad)) : smem;
                af1.u4 = *(const uint4*)p1;
            }
            auto body = [&](const U16B (&w2u)[2], const f32x4 (&b2f)[2],
                            const U16B (&w3u)[4], const float (&b3c)[4]) {
                f32x4 a0 = b2f[0], a1 = b2f[1];
                a0 = __builtin_amdgcn_mfma_f32_16x16x32_bf16(af1.s8, w2u[0].s8, a0, 0, 0, 0);
                a1 = __builtin_amdgcn_mfma_f32_16x16x32_bf16(af1.s8, w2u[1].s8, a1, 0, 0, 0);
                uint2 pk;
                pk.x = cvtpk(fmaxf(a0[0], 0.f), fmaxf(a0[1], 0.f));
                pk.y = cvtpk(fmaxf(a0[2], 0.f), fmaxf(a0[3], 0.f));
                *(uint2*)(h2b + row * H2RS + quad * 8) = pk;
                pk.x = cvtpk(fmaxf(a1[0], 0.f), fmaxf(a1[1], 0.f));
                pk.y = cvtpk(fmaxf(a1[2], 0.f), fmaxf(a1[3], 0.f));
                *(uint2*)(h2b + row * H2RS + 32 + quad * 8) = pk;
                U16B af2;
                af2.u2[0] = *(const uint2*)(h2b + row * H2RS + quad * 16);
                af2.u2[1] = *(const uint2*)(h2b + row * H2RS + quad * 16 + 8);
#pragma unroll
                for (int ot = 0; ot < 4; ot++) {
                    f32x4 a3 = f32x4{b3c[ot], b3c[ot], b3c[ot], b3c[ot]};
                    a3 = __builtin_amdgcn_mfma_f32_16x16x32_bf16(w3u[ot].s8, af2.s8, a3, 0, 0, 0);
                    // lane(col,q) reg r = M'[c=ot*16+col][w=wid*4+pt][v=quad*4+r]
                    uint2 mv;
                    mv.x = cvtpk(fmaxf(a3[0], 0.f), fmaxf(a3[1], 0.f));
                    mv.y = cvtpk(fmaxf(a3[2], 0.f), fmaxf(a3[3], 0.f));
                    *(uint2*)(msb + ms_off(ot * 16 + col, wid * 4 + pt, quad >> 1) +
                              (quad & 1) * 8) = mv;
                }
            };
            if (fg[pt]) body(w2u_h, b2f_h, w3u_h, b3c_h);
            else        body(w2u_n, b2f_n, w3u_n, b3c_n);
        }
    };

    // ---- one pingpong iteration: PhaseB(vcc) || PhaseA(vcc+1), one barrier ----
    auto iter = [&](int vcc, uint4 (&xcur)[16], uint4 (&xnxt)[16]) {
        if (vcc < 15) {  // register-prefetch xcb fragments for vcc+1
            const short* xb = (const short*)xcb +
                (((size_t)n * 64) * 16 + col) * 256 + (vcc + 1) * 16 + (quad & 1) * 8;
#pragma unroll
            for (int cl = 0; cl < 16; cl++)
                xnxt[cl] = *(const uint4*)(xb + (size_t)(wid * 16 + cl) * 4096);
        }
        // Phase B: contraction for chunk vcc from Ms[vcc&1]
        {
            const char* msb = smem + LDS_MS + (vcc & 1) * MSBUF;
#pragma unroll
            for (int cl = 0; cl < 16; cl++) {
                int c = wid * 16 + cl;
                U16B af; af.u4 = xcur[cl];
                const char* bp = (quad < 2)
                    ? (const char*)(msb + ms_off(c, col, quad))
                    : (const char*)smem;  // zero block nulls k>=16
                U16B bf; bf.u4 = *(const uint4*)bp;
                acc[cl] = __builtin_amdgcn_mfma_f32_16x16x32_bf16(af.s8, bf.s8, acc[cl], 0, 0, 0);
            }
        }
        if (vcc < 15) phaseA(vcc + 1);  // -> Ms[(vcc+1)&1], overlaps Phase B above
        __syncthreads();  // Ms[nxt] ready AND Ms[cur] reads drained
    };

    // prologue: prefetch xcb for vc=0, produce Ms[0]
    uint4 xpfA[16], xpfB[16];
    {
        const short* xb = (const short*)xcb +
            (((size_t)n * 64) * 16 + col) * 256 + 0 * 16 + (quad & 1) * 8;
#pragma unroll
        for (int cl = 0; cl < 16; cl++)
            xpfA[cl] = *(const uint4*)(xb + (size_t)(wid * 16 + cl) * 4096);
    }
    phaseA(0);
    __syncthreads();

    for (int vc = 0; vc < 16; vc += 2) {
        iter(vc, xpfA, xpfB);
        iter(vc + 1, xpfB, xpfA);
    }

    // ---- degree norm: reduce asum over the 16 col-lanes (same w per group) ----
    float s = asum;
    s += __shfl_xor(s, 1);
    s += __shfl_xor(s, 2);
    s += __shfl_xor(s, 4);
    s += __shfl_xor(s, 8);
    float* dls = (float*)(smem + LDS_H0);  // h regions dead; reuse 64 B
    if (col == 0) dls[wid * 4 + quad] = 1.f / (s + 0.001f);
    __syncthreads();
    float dlw = dls[col];  // epilogue lane's w = wt*16+col

    // epilogue: D col = w, rows quad*4+r = t (R3-verified convention)
#pragma unroll
    for (int cl = 0; cl < 16; cl++) {
        int c = wid * 16 + cl;
#pragma unroll
        for (int r = 0; r < 4; r++)
            out[(((size_t)n * 64 + c) * 16 + quad * 4 + r) * 256 + wt * 16 + col] =
                acc[cl][r] * dlw;
    }
}

// ---------------------------------------------------------------------------
extern "C" void kernel_launch(void* const* d_in, const int* in_sizes, int n_in,
                              void* d_out, int out_size, void* d_ws, size_t ws_size,
                              hipStream_t stream)
{
    const float* x      = (const float*)d_in[0];
    const float* A      = (const float*)d_in[1];
    const float* hmask  = (const float*)d_in[2];
    const float* conv_w = (const float*)d_in[4];
    const float* conv_b = (const float*)d_in[5];
    const float* nh_w1 = (const float*)d_in[6];
    const float* nh_b1 = (const float*)d_in[7];
    const float* nh_w2 = (const float*)d_in[8];
    const float* nh_b2 = (const float*)d_in[9];
    const float* nh_w3 = (const float*)d_in[10];
    const float* nh_b3 = (const float*)d_in[11];
    const float* h_w1 = (const float*)d_in[12];
    const float* h_b1 = (const float*)d_in[13];
    const float* h_w2 = (const float*)d_in[14];
    const float* h_b2 = (const float*)d_in[15];
    const float* h_w3 = (const float*)d_in[16];
    const float* h_b3 = (const float*)d_in[17];

    float* out  = (float*)d_out;
    float* outA = out + (size_t)NB * CC * TT * VV;

    __hip_bfloat16* xcb = (__hip_bfloat16*)d_ws;  // 16.8 MB

    k_copyA<<<dim3(NB, 40), 256, 0, stream>>>((const float4*)A, (float4*)outA);
    k_xc<<<dim3(NB, 16), 256, 0, stream>>>(x, conv_w, conv_b, xcb);
    k_fuse<<<dim3(NB, 16), 256, 0, stream>>>(
        A, hmask, xcb,
        nh_w1, nh_b1, nh_w2, nh_b2, nh_w3, nh_b3,
        h_w1, h_b1, h_w2, h_b2, h_w3, h_b3, out);
}

// Round 5
// 342.911 us; speedup vs baseline: 2.9454x; 2.9454x over previous
//
#include <hip/hip_runtime.h>
#include <hip/hip_bf16.h>
#include <cstddef>

#define NB 32
#define CC 64
#define TT 16
#define VV 256
#define KK 5

typedef __attribute__((ext_vector_type(8))) short short8;
typedef __attribute__((ext_vector_type(4))) float f32x4;

union U16B { short8 s8; uint2 u2[2]; uint4 u4; unsigned u[4]; unsigned short us[8]; };

__device__ inline unsigned short f2bf(float f) {
    unsigned u = __float_as_uint(f);
    return (unsigned short)((u + 0x7fffu + ((u >> 16) & 1u)) >> 16);
}
// packed bf16 convert (RNE, same rounding as f2bf): low = a, high = b
__device__ inline unsigned cvtpk(float a, float b) {
    unsigned r;
    asm("v_cvt_pk_bf16_f32 %0, %1, %2" : "=v"(r) : "v"(a), "v"(b));
    return r;
}

// ---------------------------------------------------------------------------
// K1: pure vectorized copy A -> out tail (degree sums computed in k_fuse).
__global__ __launch_bounds__(256) void k_copyA(const float4* __restrict__ A4,
                                               float4* __restrict__ outA4)
{
    int n = blockIdx.x, rb = blockIdx.y, t = threadIdx.x;
    size_t base = (size_t)n * (KK * VV * VV / 4) + (size_t)rb * (32 * 64)
                + (size_t)(t >> 6) * (8 * 64) + (t & 63);
#pragma unroll
    for (int i = 0; i < 8; i++)
        outA4[base + i * 64] = A4[base + i * 64];
}

// ---------------------------------------------------------------------------
// K2: xcb[n,c,t,v] = bf16( sum_ci Wc[c,ci]*x[n,ci,t,v] + bc[c] )
__global__ __launch_bounds__(256) void k_xc(const float* __restrict__ x,
                                            const float* __restrict__ Wc,
                                            const float* __restrict__ bc,
                                            __hip_bfloat16* __restrict__ xcb)
{
    __shared__ float WT[64 * 64];  // WT[ci][co]
    __shared__ float bs[64];
    int n = blockIdx.x, tid = threadIdx.x;
    int p = blockIdx.y * 256 + tid;  // t*256+v index
    for (int i = tid; i < 4096; i += 256) WT[(i & 63) * 64 + (i >> 6)] = Wc[i];
    if (tid < 64) bs[tid] = bc[tid];
    __syncthreads();

    float acc[64];
#pragma unroll
    for (int c = 0; c < 64; c++) acc[c] = bs[c];
#pragma unroll 4
    for (int ci = 0; ci < 64; ci++) {
        float xv = x[((size_t)n * 64 + ci) * 4096 + p];
        const float4* wr = (const float4*)&WT[ci * 64];
#pragma unroll
        for (int q = 0; q < 16; q++) {
            float4 w4 = wr[q];
            acc[q * 4 + 0] = fmaf(w4.x, xv, acc[q * 4 + 0]);
            acc[q * 4 + 1] = fmaf(w4.y, xv, acc[q * 4 + 1]);
            acc[q * 4 + 2] = fmaf(w4.z, xv, acc[q * 4 + 2]);
            acc[q * 4 + 3] = fmaf(w4.w, xv, acc[q * 4 + 3]);
        }
    }
#pragma unroll
    for (int c = 0; c < 64; c++)
        xcb[((size_t)n * 64 + c) * 4096 + p] = __float2bfloat16(acc[c]);
}

// ---------------------------------------------------------------------------
// K3 fused v5 (round-3 verified structure + zero-VGPR xcb staging):
//  per vc: [issue global_load_lds xcb stage] -> PhaseA -> barrier (drains the
//  staging loads for free) -> PhaseB (af from LDS) -> barrier.
// LDS layout:
//  [0,16)  zero block
//  h1: per wave 64 rows x 32B, pair-XOR swizzle     (2048 / wave)
//  h2: per wave 64 rows x 72B (verified layout)     (4608 / wave)
//  Ms: 64 ch x 34 units x 16B (EVEN unit stride -> bijective u^1 swizzle;
//      verified absmax-clean in round 4)            (34816)
//  Xs: xcb stage, 4 waves x 8 KB linear             (32768)
#define H1SZ 2048
#define H2RS 72
#define HWAVE (H1SZ + 64 * H2RS)           // 6656
#define MS_UST 34                           // 16B units per channel
#define MSBUF (64 * MS_UST * 16)            // 34816 bytes
#define LDS_H0 16
#define LDS_MS (LDS_H0 + 4 * HWAVE)         // 26640
#define XST (LDS_MS + MSBUF)                // 61456
#define LDS_TOTAL (XST + 32768)             // 94224

// h1 byte offset within a wave's h1 region: row in [0,64), 16B-half h in {0,1}
__device__ inline int h1_off(int row, int h) {
    int u = row * 2 + h;
    u ^= (row >> 2) & 1;
    return u * 16;
}
// Ms byte offset: channel C in [0,64), w in [0,16), v3 = (v>>3) in {0,1}
// u = C*34 + w*2 + v3 in [C*34, C*34+32); base even => u^1 stays in-block.
__device__ inline int ms_off(int C, int w, int v3) {
    int u = C * MS_UST + w * 2 + v3;
    u ^= (w >> 2) & 1;
    return u * 16;
}

__global__ __launch_bounds__(256) void k_fuse(
    const float* __restrict__ A, const float* __restrict__ hm,
    const __hip_bfloat16* __restrict__ xcb,
    const float* __restrict__ nh_w1, const float* __restrict__ nh_b1,
    const float* __restrict__ nh_w2, const float* __restrict__ nh_b2,
    const float* __restrict__ nh_w3, const float* __restrict__ nh_b3,
    const float* __restrict__ h_w1, const float* __restrict__ h_b1,
    const float* __restrict__ h_w2, const float* __restrict__ h_b2,
    const float* __restrict__ h_w3, const float* __restrict__ h_b3,
    float* __restrict__ out)
{
    __shared__ char smem[LDS_TOTAL];
    int tid = threadIdx.x, lane = tid & 63, wid = tid >> 6;
    int n = blockIdx.x, wt = blockIdx.y;
    int col = lane & 15, quad = lane >> 4;
    int vl = col;  // Phase A lane role: point (w = wid*4+quad, v-local=vl)

    char* h1b = smem + LDS_H0 + wid * HWAVE;
    char* h2b = h1b + H1SZ;
    char* xsb = smem + XST + wid * 8192;  // this wave's xcb stage

    if (tid < 4) ((unsigned*)smem)[tid] = 0;  // shared 16B zero block

    int w_lane = wt * 16 + wid * 4 + quad;
    bool flag_lane = hm[n * 256 + w_lane] > 0.5f;

    // group (per-pt) branch flags (wave-uniform)
    bool fg[4];
#pragma unroll
    for (int g = 0; g < 4; g++)
        fg[g] = hm[n * 256 + wt * 16 + wid * 4 + g] > 0.5f;

    // staging source decomposition for this lane (see layout identity below)
    int st_subcl = lane >> 5, st_vh = (lane >> 4) & 1, st_t = lane & 15;
    const short* st_base = (const short*)xcb +
        (((size_t)n * 64 + wid * 16 + st_subcl) * 16 + st_t) * 256 + st_vh * 8;

    // --- weight fragments for BOTH branches (VGPR-resident, loaded once) ---
    U16B w2u_n[2], w2u_h[2], w3u_n[4], w3u_h[4];
    f32x4 b2f_n[2], b2f_h[2];
    float b3c_n[4], b3c_h[4];
#pragma unroll
    for (int ot = 0; ot < 2; ot++) {
#pragma unroll
        for (int j = 0; j < 8; j++) {
            int k = quad * 8 + j;
            w2u_n[ot].us[j] = (k < 16) ? f2bf(nh_w2[(ot * 16 + col) * 16 + k]) : (unsigned short)0;
            w2u_h[ot].us[j] = (k < 16) ? f2bf(h_w2[(ot * 16 + col) * 16 + k]) : (unsigned short)0;
        }
#pragma unroll
        for (int r = 0; r < 4; r++) {
            b2f_n[ot][r] = nh_b2[ot * 16 + quad * 4 + r];
            b2f_h[ot][r] = h_b2[ot * 16 + quad * 4 + r];
        }
    }
#pragma unroll
    for (int ot = 0; ot < 4; ot++) {
#pragma unroll
        for (int j = 0; j < 8; j++) {
            w3u_n[ot].us[j] = f2bf(nh_w3[(ot * 16 + col) * 32 + quad * 8 + j]);
            w3u_h[ot].us[j] = f2bf(h_w3[(ot * 16 + col) * 32 + quad * 8 + j]);
        }
        // L3 swapped-operand output: lane's channel is ot*16+col -> scalar bias
        b3c_n[ot] = nh_b3[ot * 16 + col];
        b3c_h[ot] = h_b3[ot * 16 + col];
    }

    f32x4 acc[16];
#pragma unroll
    for (int i = 0; i < 16; i++) acc[i] = f32x4{0.f, 0.f, 0.f, 0.f};

    float asum = 0.f;  // per-lane partial of sum_{k,v} A[n,k,v,w_lane]

    __syncthreads();  // zero block visible

    // prefetch A for vc=0
    float a_cur[5];
#pragma unroll
    for (int k = 0; k < 5; k++)
        a_cur[k] = A[(((size_t)n * 5 + k) * 256 + vl) * 256 + w_lane];

    for (int vc = 0; vc < 16; vc++) {
        // ---- issue xcb -> LDS staging for this vc (async, zero VGPR cost;
        //      lands during Phase A; barrier below drains it for free).
        //      lane l of wave wid loads 16B of xcb[n, wid*16+clp*2+(l>>5),
        //      t=l&15, v=vc*16+((l>>4)&1)*8 ..+8] into xsb + clp*1024 + l*16.
        {
            const short* g0 = st_base + vc * 16;
#pragma unroll
            for (int clp = 0; clp < 8; clp++) {
                __builtin_amdgcn_global_load_lds(
                    (const __attribute__((address_space(1))) unsigned*)(g0 + (size_t)clp * 2 * 4096),
                    (__attribute__((address_space(3))) unsigned*)(xsb + clp * 1024),
                    16, 0, 0);
            }
        }
        // ================= Phase A: MLP -> M-LDS =================
        {
            float a[5];
#pragma unroll
            for (int k = 0; k < 5; k++) { a[k] = a_cur[k]; asum += a[k]; }

            // prefetch next vc's A values (in flight across this iteration)
            if (vc < 15) {
                int v = (vc + 1) * 16 + vl;
#pragma unroll
                for (int k = 0; k < 5; k++)
                    a_cur[k] = A[(((size_t)n * 5 + k) * 256 + v) * 256 + w_lane];
            }

            float h1s[16];
#pragma unroll
            for (int o = 0; o < 16; o++) {
                float sn = nh_b1[o], sh = h_b1[o];
#pragma unroll
                for (int k = 0; k < 5; k++) {
                    sn = fmaf(nh_w1[o * 5 + k], a[k], sn);
                    sh = fmaf(h_w1[o * 5 + k], a[k], sh);
                }
                h1s[o] = flag_lane ? fmaxf(sh, 0.f) : fmaxf(sn, 0.f);
            }
            uint4 q0, q1;
            q0.x = cvtpk(h1s[0], h1s[1]);   q0.y = cvtpk(h1s[2], h1s[3]);
            q0.z = cvtpk(h1s[4], h1s[5]);   q0.w = cvtpk(h1s[6], h1s[7]);
            q1.x = cvtpk(h1s[8], h1s[9]);   q1.y = cvtpk(h1s[10], h1s[11]);
            q1.z = cvtpk(h1s[12], h1s[13]); q1.w = cvtpk(h1s[14], h1s[15]);
            *(uint4*)(h1b + h1_off(lane, 0)) = q0;
            *(uint4*)(h1b + h1_off(lane, 1)) = q1;

#pragma unroll
            for (int pt = 0; pt < 4; pt++) {
                int row = pt * 16 + col;
                U16B af1;
                {
                    const char* p1 = (quad < 2) ? (h1b + h1_off(row, quad)) : smem;
                    af1.u4 = *(const uint4*)p1;
                }
                auto body = [&](const U16B (&w2u)[2], const f32x4 (&b2f)[2],
                                const U16B (&w3u)[4], const float (&b3c)[4]) {
                    f32x4 a0 = b2f[0], a1 = b2f[1];
                    a0 = __builtin_amdgcn_mfma_f32_16x16x32_bf16(af1.s8, w2u[0].s8, a0, 0, 0, 0);
                    a1 = __builtin_amdgcn_mfma_f32_16x16x32_bf16(af1.s8, w2u[1].s8, a1, 0, 0, 0);
                    uint2 pk;
                    pk.x = cvtpk(fmaxf(a0[0], 0.f), fmaxf(a0[1], 0.f));
                    pk.y = cvtpk(fmaxf(a0[2], 0.f), fmaxf(a0[3], 0.f));
                    *(uint2*)(h2b + row * H2RS + quad * 8) = pk;
                    pk.x = cvtpk(fmaxf(a1[0], 0.f), fmaxf(a1[1], 0.f));
                    pk.y = cvtpk(fmaxf(a1[2], 0.f), fmaxf(a1[3], 0.f));
                    *(uint2*)(h2b + row * H2RS + 32 + quad * 8) = pk;
                    U16B af2;
                    af2.u2[0] = *(const uint2*)(h2b + row * H2RS + quad * 16);
                    af2.u2[1] = *(const uint2*)(h2b + row * H2RS + quad * 16 + 8);
#pragma unroll
                    for (int ot = 0; ot < 4; ot++) {
                        f32x4 a3 = f32x4{b3c[ot], b3c[ot], b3c[ot], b3c[ot]};
                        a3 = __builtin_amdgcn_mfma_f32_16x16x32_bf16(w3u[ot].s8, af2.s8, a3, 0, 0, 0);
                        // lane(col,q) reg r = M'[c=ot*16+col][w=wid*4+pt][v=quad*4+r]
                        uint2 mv;
                        mv.x = cvtpk(fmaxf(a3[0], 0.f), fmaxf(a3[1], 0.f));
                        mv.y = cvtpk(fmaxf(a3[2], 0.f), fmaxf(a3[3], 0.f));
                        *(uint2*)(smem + LDS_MS +
                                  ms_off(ot * 16 + col, wid * 4 + pt, quad >> 1) +
                                  (quad & 1) * 8) = mv;
                    }
                };
                if (fg[pt]) body(w2u_h, b2f_h, w3u_h, b3c_h);
                else        body(w2u_n, b2f_n, w3u_n, b3c_n);
            }
        }
        __syncthreads();  // M tile ready AND staging loads drained
        // ================= Phase B: contraction (af from LDS stage) =========
        {
#pragma unroll
            for (int cl = 0; cl < 16; cl++) {
                int c = wid * 16 + cl;
                U16B af;
                af.u4 = *(const uint4*)(xsb + (cl >> 1) * 1024 +
                                        (((cl & 1) * 32 + (quad & 1) * 16 + col) * 16));
                const char* bp = (quad < 2)
                    ? (const char*)(smem + LDS_MS + ms_off(c, col, quad))
                    : (const char*)smem;  // zero block nulls k>=16
                U16B bf; bf.u4 = *(const uint4*)bp;
                acc[cl] = __builtin_amdgcn_mfma_f32_16x16x32_bf16(af.s8, bf.s8, acc[cl], 0, 0, 0);
            }
        }
        __syncthreads();  // before next vc overwrites Ms and Xs
    }

    // ---- degree norm: reduce asum over the 16 col-lanes (same w per group) ----
    float s = asum;
    s += __shfl_xor(s, 1);
    s += __shfl_xor(s, 2);
    s += __shfl_xor(s, 4);
    s += __shfl_xor(s, 8);
    float* dls = (float*)(smem + LDS_H0);  // h regions dead; reuse 64 B
    if (col == 0) dls[wid * 4 + quad] = 1.f / (s + 0.001f);
    __syncthreads();
    float dlw = dls[col];  // epilogue lane's w = wt*16+col

    // epilogue: D col = w, rows quad*4+r = t (R3-verified convention)
#pragma unroll
    for (int cl = 0; cl < 16; cl++) {
        int c = wid * 16 + cl;
#pragma unroll
        for (int r = 0; r < 4; r++)
            out[(((size_t)n * 64 + c) * 16 + quad * 4 + r) * 256 + wt * 16 + col] =
                acc[cl][r] * dlw;
    }
}

// ---------------------------------------------------------------------------
extern "C" void kernel_launch(void* const* d_in, const int* in_sizes, int n_in,
                              void* d_out, int out_size, void* d_ws, size_t ws_size,
                              hipStream_t stream)
{
    const float* x      = (const float*)d_in[0];
    const float* A      = (const float*)d_in[1];
    const float* hmask  = (const float*)d_in[2];
    const float* conv_w = (const float*)d_in[4];
    const float* conv_b = (const float*)d_in[5];
    const float* nh_w1 = (const float*)d_in[6];
    const float* nh_b1 = (const float*)d_in[7];
    const float* nh_w2 = (const float*)d_in[8];
    const float* nh_b2 = (const float*)d_in[9];
    const float* nh_w3 = (const float*)d_in[10];
    const float* nh_b3 = (const float*)d_in[11];
    const float* h_w1 = (const float*)d_in[12];
    const float* h_b1 = (const float*)d_in[13];
    const float* h_w2 = (const float*)d_in[14];
    const float* h_b2 = (const float*)d_in[15];
    const float* h_w3 = (const float*)d_in[16];
    const float* h_b3 = (const float*)d_in[17];

    float* out  = (float*)d_out;
    float* outA = out + (size_t)NB * CC * TT * VV;

    __hip_bfloat16* xcb = (__hip_bfloat16*)d_ws;  // 16.8 MB

    k_copyA<<<dim3(NB, 40), 256, 0, stream>>>((const float4*)A, (float4*)outA);
    k_xc<<<dim3(NB, 16), 256, 0, stream>>>(x, conv_w, conv_b, xcb);
    k_fuse<<<dim3(NB, 16), 256, 0, stream>>>(
        A, hmask, xcb,
        nh_w1, nh_b1, nh_w2, nh_b2, nh_w3, nh_b3,
        h_w1, h_b1, h_w2, h_b2, h_w3, h_b3, out);
}

// Round 6
// 278.146 us; speedup vs baseline: 3.6312x; 1.2328x over previous
//
#include <hip/hip_runtime.h>
#include <hip/hip_bf16.h>
#include <cstddef>

#define NB 32
#define CC 64
#define TT 16
#define VV 256
#define KK 5

typedef __attribute__((ext_vector_type(8))) short short8;
typedef __attribute__((ext_vector_type(4))) float f32x4;

union U16B { short8 s8; uint2 u2[2]; uint4 u4; unsigned u[4]; unsigned short us[8]; };

__device__ inline unsigned short f2bf(float f) {
    unsigned u = __float_as_uint(f);
    return (unsigned short)((u + 0x7fffu + ((u >> 16) & 1u)) >> 16);
}
// packed bf16 convert (RNE, same rounding as f2bf): low = a, high = b
__device__ inline unsigned cvtpk(float a, float b) {
    unsigned r;
    asm("v_cvt_pk_bf16_f32 %0, %1, %2" : "=v"(r) : "v"(a), "v"(b));
    return r;
}

// ---------------------------------------------------------------------------
// K1 merged: blockIdx.y < 16 -> xc blocks; >= 16 -> A-copy blocks.
__global__ __launch_bounds__(256) void k_pre(const float* __restrict__ x,
                                             const float* __restrict__ Wc,
                                             const float* __restrict__ bc,
                                             __hip_bfloat16* __restrict__ xcb,
                                             const float4* __restrict__ A4,
                                             float4* __restrict__ outA4)
{
    if (blockIdx.y >= 16) {
        // ---- pure vectorized copy A -> out tail ----
        int n = blockIdx.x, rb = blockIdx.y - 16, t = threadIdx.x;
        size_t base = (size_t)n * (KK * VV * VV / 4) + (size_t)rb * (32 * 64)
                    + (size_t)(t >> 6) * (8 * 64) + (t & 63);
#pragma unroll
        for (int i = 0; i < 8; i++)
            outA4[base + i * 64] = A4[base + i * 64];
        return;
    }
    // ---- xcb[n,c,t,v] = bf16( sum_ci Wc[c,ci]*x[n,ci,t,v] + bc[c] ) ----
    __shared__ float WT[64 * 64];  // WT[ci][co]
    __shared__ float bs[64];
    int n = blockIdx.x, tid = threadIdx.x;
    int p = blockIdx.y * 256 + tid;  // t*256+v index
    for (int i = tid; i < 4096; i += 256) WT[(i & 63) * 64 + (i >> 6)] = Wc[i];
    if (tid < 64) bs[tid] = bc[tid];
    __syncthreads();

    float acc[64];
#pragma unroll
    for (int c = 0; c < 64; c++) acc[c] = bs[c];
#pragma unroll 4
    for (int ci = 0; ci < 64; ci++) {
        float xv = x[((size_t)n * 64 + ci) * 4096 + p];
        const float4* wr = (const float4*)&WT[ci * 64];
#pragma unroll
        for (int q = 0; q < 16; q++) {
            float4 w4 = wr[q];
            acc[q * 4 + 0] = fmaf(w4.x, xv, acc[q * 4 + 0]);
            acc[q * 4 + 1] = fmaf(w4.y, xv, acc[q * 4 + 1]);
            acc[q * 4 + 2] = fmaf(w4.z, xv, acc[q * 4 + 2]);
            acc[q * 4 + 3] = fmaf(w4.w, xv, acc[q * 4 + 3]);
        }
    }
#pragma unroll
    for (int c = 0; c < 64; c++)
        xcb[((size_t)n * 64 + c) * 4096 + p] = __float2bfloat16(acc[c]);
}

// ---------------------------------------------------------------------------
// K3 fused v6: producer/consumer wave specialization, 512 threads.
//  waves 0-3 (producers): Phase A (MLP -> Ms[parity]) only.
//  waves 4-7 (consumers): xcb staging + Phase B (contraction) only.
//  One barrier per vc; Ms AND Xs double-buffered; per SIMD 1 producer wave
//  (VALU-heavy) + 1 consumer wave (MFMA/LDS-heavy) overlap on separate pipes.
// LDS layout (157,712 B total):
//  [0,16)                        zero block
//  h1: 4 prod waves x 2048       (pair-XOR swizzle, verified)
//  h2: 4 prod waves x 64 x 72    (verified layout)
//  Ms: 2 x 64ch x 32 units x 16B (c-XOR swizzle: u = C*32 + ((w*2+v3)^(C&7));
//                                 bijective per channel; dense 512B spans on
//                                 both write and read -> conflict-free)
//  Xs: 2 x 4 cons waves x 8KB    (linear, global_load_lds target)
#define H1SZ 2048
#define H2RS 72
#define HWAVE (H1SZ + 64 * H2RS)            // 6656
#define LDS_H0 16
#define LDS_MS (LDS_H0 + 4 * HWAVE)         // 26640
#define MSBUF (64 * 32 * 16)                // 32768
#define LDS_XS (LDS_MS + 2 * MSBUF)         // 92176
#define XSBUF 32768
#define LDS_TOTAL (LDS_XS + 2 * XSBUF)      // 157712

// h1 byte offset within a wave's h1 region: row in [0,64), 16B-half h in {0,1}
__device__ inline int h1_off(int row, int h) {
    int u = row * 2 + h;
    u ^= (row >> 2) & 1;
    return u * 16;
}
// Ms byte offset: channel C in [0,64), w in [0,16), v3 = (v>>3) in {0,1}
__device__ inline int ms_off(int C, int w, int v3) {
    int u = (C << 5) | (((w << 1) | v3) ^ (C & 7));
    return u * 16;
}

__global__ __launch_bounds__(512, 2) void k_fuse(
    const float* __restrict__ A, const float* __restrict__ hm,
    const __hip_bfloat16* __restrict__ xcb,
    const float* __restrict__ nh_w1, const float* __restrict__ nh_b1,
    const float* __restrict__ nh_w2, const float* __restrict__ nh_b2,
    const float* __restrict__ nh_w3, const float* __restrict__ nh_b3,
    const float* __restrict__ h_w1, const float* __restrict__ h_b1,
    const float* __restrict__ h_w2, const float* __restrict__ h_b2,
    const float* __restrict__ h_w3, const float* __restrict__ h_b3,
    float* __restrict__ out)
{
    __shared__ char smem[LDS_TOTAL];
    int tid = threadIdx.x, lane = tid & 63, wid = tid >> 6;  // wid 0..7
    int n = blockIdx.x, wt = blockIdx.y;
    int col = lane & 15, quad = lane >> 4;
    bool is_prod = (wid < 4);
    int pwid = wid & 3;   // producer wave id / consumer wave id (cwid)

    char* h1b = smem + LDS_H0 + pwid * HWAVE;
    char* h2b = h1b + H1SZ;

    if (tid < 4) ((unsigned*)smem)[tid] = 0;  // shared 16B zero block

    // ---------------- per-role state ----------------
    int w_lane = 0;
    bool flag_lane = false;
    bool fg[4] = {false, false, false, false};
    U16B w2u_n[2], w2u_h[2], w3u_n[4], w3u_h[4];
    f32x4 b2f_n[2], b2f_h[2];
    float b3c_n[4], b3c_h[4];
    float a_cur[5] = {0, 0, 0, 0, 0};
    float asum = 0.f;
    const short* st_base = nullptr;

    if (is_prod) {
        w_lane = wt * 16 + pwid * 4 + quad;
        flag_lane = hm[n * 256 + w_lane] > 0.5f;
#pragma unroll
        for (int g = 0; g < 4; g++)
            fg[g] = hm[n * 256 + wt * 16 + pwid * 4 + g] > 0.5f;
#pragma unroll
        for (int ot = 0; ot < 2; ot++) {
#pragma unroll
            for (int j = 0; j < 8; j++) {
                int k = quad * 8 + j;
                w2u_n[ot].us[j] = (k < 16) ? f2bf(nh_w2[(ot * 16 + col) * 16 + k]) : (unsigned short)0;
                w2u_h[ot].us[j] = (k < 16) ? f2bf(h_w2[(ot * 16 + col) * 16 + k]) : (unsigned short)0;
            }
#pragma unroll
            for (int r = 0; r < 4; r++) {
                b2f_n[ot][r] = nh_b2[ot * 16 + quad * 4 + r];
                b2f_h[ot][r] = h_b2[ot * 16 + quad * 4 + r];
            }
        }
#pragma unroll
        for (int ot = 0; ot < 4; ot++) {
#pragma unroll
            for (int j = 0; j < 8; j++) {
                w3u_n[ot].us[j] = f2bf(nh_w3[(ot * 16 + col) * 32 + quad * 8 + j]);
                w3u_h[ot].us[j] = f2bf(h_w3[(ot * 16 + col) * 32 + quad * 8 + j]);
            }
            b3c_n[ot] = nh_b3[ot * 16 + col];
            b3c_h[ot] = h_b3[ot * 16 + col];
        }
        // prefetch A for vc=0 (v = col, w = w_lane)
#pragma unroll
        for (int k = 0; k < 5; k++)
            a_cur[k] = A[(((size_t)n * 5 + k) * 256 + col) * 256 + w_lane];
    } else {
        // staging source decomposition (verified layout identity, round 5)
        int st_subcl = lane >> 5, st_vh = (lane >> 4) & 1, st_t = lane & 15;
        st_base = (const short*)xcb +
            (((size_t)n * 64 + pwid * 16 + st_subcl) * 16 + st_t) * 256 + st_vh * 8;
    }

    f32x4 acc[16];
#pragma unroll
    for (int i = 0; i < 16; i++) acc[i] = f32x4{0.f, 0.f, 0.f, 0.f};

    // ---- Phase A for chunk vcc -> Ms[vcc&1] (producers only) ----
    auto phaseA = [&](int vcc) {
        char* msb = smem + LDS_MS + (vcc & 1) * MSBUF;
        float a[5];
#pragma unroll
        for (int k = 0; k < 5; k++) { a[k] = a_cur[k]; asum += a[k]; }

        if (vcc < 15) {  // prefetch next chunk's A
            int v = (vcc + 1) * 16 + col;
#pragma unroll
            for (int k = 0; k < 5; k++)
                a_cur[k] = A[(((size_t)n * 5 + k) * 256 + v) * 256 + w_lane];
        }

        float h1s[16];
#pragma unroll
        for (int o = 0; o < 16; o++) {
            float sn = nh_b1[o], sh = h_b1[o];
#pragma unroll
            for (int k = 0; k < 5; k++) {
                sn = fmaf(nh_w1[o * 5 + k], a[k], sn);
                sh = fmaf(h_w1[o * 5 + k], a[k], sh);
            }
            h1s[o] = flag_lane ? fmaxf(sh, 0.f) : fmaxf(sn, 0.f);
        }
        uint4 q0, q1;
        q0.x = cvtpk(h1s[0], h1s[1]);   q0.y = cvtpk(h1s[2], h1s[3]);
        q0.z = cvtpk(h1s[4], h1s[5]);   q0.w = cvtpk(h1s[6], h1s[7]);
        q1.x = cvtpk(h1s[8], h1s[9]);   q1.y = cvtpk(h1s[10], h1s[11]);
        q1.z = cvtpk(h1s[12], h1s[13]); q1.w = cvtpk(h1s[14], h1s[15]);
        *(uint4*)(h1b + h1_off(lane, 0)) = q0;
        *(uint4*)(h1b + h1_off(lane, 1)) = q1;

#pragma unroll
        for (int pt = 0; pt < 4; pt++) {
            int row = pt * 16 + col;
            U16B af1;
            {
                const char* p1 = (quad < 2) ? (h1b + h1_off(row, quad)) : smem;
                af1.u4 = *(const uint4*)p1;
            }
            auto body = [&](const U16B (&w2u)[2], const f32x4 (&b2f)[2],
                            const U16B (&w3u)[4], const float (&b3c)[4]) {
                f32x4 a0 = b2f[0], a1 = b2f[1];
                a0 = __builtin_amdgcn_mfma_f32_16x16x32_bf16(af1.s8, w2u[0].s8, a0, 0, 0, 0);
                a1 = __builtin_amdgcn_mfma_f32_16x16x32_bf16(af1.s8, w2u[1].s8, a1, 0, 0, 0);
                uint2 pk;
                pk.x = cvtpk(fmaxf(a0[0], 0.f), fmaxf(a0[1], 0.f));
                pk.y = cvtpk(fmaxf(a0[2], 0.f), fmaxf(a0[3], 0.f));
                *(uint2*)(h2b + row * H2RS + quad * 8) = pk;
                pk.x = cvtpk(fmaxf(a1[0], 0.f), fmaxf(a1[1], 0.f));
                pk.y = cvtpk(fmaxf(a1[2], 0.f), fmaxf(a1[3], 0.f));
                *(uint2*)(h2b + row * H2RS + 32 + quad * 8) = pk;
                U16B af2;
                af2.u2[0] = *(const uint2*)(h2b + row * H2RS + quad * 16);
                af2.u2[1] = *(const uint2*)(h2b + row * H2RS + quad * 16 + 8);
#pragma unroll
                for (int ot = 0; ot < 4; ot++) {
                    f32x4 a3 = f32x4{b3c[ot], b3c[ot], b3c[ot], b3c[ot]};
                    a3 = __builtin_amdgcn_mfma_f32_16x16x32_bf16(w3u[ot].s8, af2.s8, a3, 0, 0, 0);
                    // lane(col,q) reg r = M'[c=ot*16+col][w=pwid*4+pt][v=quad*4+r]
                    uint2 mv;
                    mv.x = cvtpk(fmaxf(a3[0], 0.f), fmaxf(a3[1], 0.f));
                    mv.y = cvtpk(fmaxf(a3[2], 0.f), fmaxf(a3[3], 0.f));
                    *(uint2*)(msb + ms_off(ot * 16 + col, pwid * 4 + pt, quad >> 1) +
                              (quad & 1) * 8) = mv;
                }
            };
            if (fg[pt]) body(w2u_h, b2f_h, w3u_h, b3c_h);
            else        body(w2u_n, b2f_n, w3u_n, b3c_n);
        }
    };

    // ---- staging issue for chunk vcc -> Xs[vcc&1] (consumers only) ----
    auto stage = [&](int vcc) {
        char* xsb_w = smem + LDS_XS + (vcc & 1) * XSBUF + pwid * 8192;
        const short* g0 = st_base + vcc * 16;
#pragma unroll
        for (int clp = 0; clp < 8; clp++) {
            __builtin_amdgcn_global_load_lds(
                (const __attribute__((address_space(1))) unsigned*)(g0 + (size_t)clp * 2 * 4096),
                (__attribute__((address_space(3))) unsigned*)(xsb_w + clp * 1024),
                16, 0, 0);
        }
    };

    // ---- Phase B for chunk vcc from Ms[vcc&1], Xs[vcc&1] (consumers) ----
    auto phaseB = [&](int vcc) {
        const char* msb = smem + LDS_MS + (vcc & 1) * MSBUF;
        const char* xsb_r = smem + LDS_XS + (vcc & 1) * XSBUF + pwid * 8192;
#pragma unroll
        for (int cl = 0; cl < 16; cl++) {
            int c = pwid * 16 + cl;
            U16B af;
            af.u4 = *(const uint4*)(xsb_r + (cl >> 1) * 1024 +
                                    (((cl & 1) * 32 + (quad & 1) * 16 + col) * 16));
            const char* bp = (quad < 2)
                ? (const char*)(msb + ms_off(c, col, quad))
                : (const char*)smem;  // zero block nulls k>=16
            U16B bf; bf.u4 = *(const uint4*)bp;
            acc[cl] = __builtin_amdgcn_mfma_f32_16x16x32_bf16(af.s8, bf.s8, acc[cl], 0, 0, 0);
        }
    };

    // ---- prologue: producers make Ms[0]; consumers stage Xs[0] ----
    if (is_prod) phaseA(0);
    else         stage(0);
    __syncthreads();

    // ---- main loop: one barrier per vc ----
    for (int k = 0; k < 16; k++) {
        if (!is_prod) {
            if (k < 15) stage(k + 1);
            phaseB(k);
        } else {
            if (k < 15) phaseA(k + 1);
        }
        __syncthreads();
    }

    // ---- degree norm: producers reduce asum over the 16 col-lanes ----
    float* dls = (float*)(smem + LDS_H0);  // h regions dead; reuse 64 B
    if (is_prod) {
        float s = asum;
        s += __shfl_xor(s, 1);
        s += __shfl_xor(s, 2);
        s += __shfl_xor(s, 4);
        s += __shfl_xor(s, 8);
        if (col == 0) dls[pwid * 4 + quad] = 1.f / (s + 0.001f);
    }
    __syncthreads();

    // ---- epilogue (consumers): D col = w, rows quad*4+r = t ----
    if (!is_prod) {
        float dlw = dls[col];
#pragma unroll
        for (int cl = 0; cl < 16; cl++) {
            int c = pwid * 16 + cl;
#pragma unroll
            for (int r = 0; r < 4; r++)
                out[(((size_t)n * 64 + c) * 16 + quad * 4 + r) * 256 + wt * 16 + col] =
                    acc[cl][r] * dlw;
        }
    }
}

// ---------------------------------------------------------------------------
extern "C" void kernel_launch(void* const* d_in, const int* in_sizes, int n_in,
                              void* d_out, int out_size, void* d_ws, size_t ws_size,
                              hipStream_t stream)
{
    const float* x      = (const float*)d_in[0];
    const float* A      = (const float*)d_in[1];
    const float* hmask  = (const float*)d_in[2];
    const float* conv_w = (const float*)d_in[4];
    const float* conv_b = (const float*)d_in[5];
    const float* nh_w1 = (const float*)d_in[6];
    const float* nh_b1 = (const float*)d_in[7];
    const float* nh_w2 = (const float*)d_in[8];
    const float* nh_b2 = (const float*)d_in[9];
    const float* nh_w3 = (const float*)d_in[10];
    const float* nh_b3 = (const float*)d_in[11];
    const float* h_w1 = (const float*)d_in[12];
    const float* h_b1 = (const float*)d_in[13];
    const float* h_w2 = (const float*)d_in[14];
    const float* h_b2 = (const float*)d_in[15];
    const float* h_w3 = (const float*)d_in[16];
    const float* h_b3 = (const float*)d_in[17];

    float* out  = (float*)d_out;
    float* outA = out + (size_t)NB * CC * TT * VV;

    __hip_bfloat16* xcb = (__hip_bfloat16*)d_ws;  // 16.8 MB

    k_pre<<<dim3(NB, 56), 256, 0, stream>>>(x, conv_w, conv_b, xcb,
                                            (const float4*)A, (float4*)outA);
    k_fuse<<<dim3(NB, 16), 512, 0, stream>>>(
        A, hmask, xcb,
        nh_w1, nh_b1, nh_w2, nh_b2, nh_w3, nh_b3,
        h_w1, h_b1, h_w2, h_b2, h_w3, h_b3, out);
}

// Round 7
// 272.384 us; speedup vs baseline: 3.7080x; 1.0212x over previous
//
#include <hip/hip_runtime.h>
#include <hip/hip_bf16.h>
#include <cstddef>

#define NB 32
#define CC 64
#define TT 16
#define VV 256
#define KK 5

typedef __attribute__((ext_vector_type(8))) short short8;
typedef __attribute__((ext_vector_type(4))) float f32x4;

union U16B { short8 s8; uint2 u2[2]; uint4 u4; unsigned u[4]; unsigned short us[8]; };

__device__ inline unsigned short f2bf(float f) {
    unsigned u = __float_as_uint(f);
    return (unsigned short)((u + 0x7fffu + ((u >> 16) & 1u)) >> 16);
}
// packed bf16 convert (RNE, same rounding as f2bf): low = a, high = b
__device__ inline unsigned cvtpk(float a, float b) {
    unsigned r;
    asm("v_cvt_pk_bf16_f32 %0, %1, %2" : "=v"(r) : "v"(a), "v"(b));
    return r;
}

// ---------------------------------------------------------------------------
// K1 merged: blockIdx.y < 16 -> xc blocks; >= 16 -> A-copy blocks.
__global__ __launch_bounds__(256) void k_pre(const float* __restrict__ x,
                                             const float* __restrict__ Wc,
                                             const float* __restrict__ bc,
                                             __hip_bfloat16* __restrict__ xcb,
                                             const float4* __restrict__ A4,
                                             float4* __restrict__ outA4)
{
    if (blockIdx.y >= 16) {
        int n = blockIdx.x, rb = blockIdx.y - 16, t = threadIdx.x;
        size_t base = (size_t)n * (KK * VV * VV / 4) + (size_t)rb * (32 * 64)
                    + (size_t)(t >> 6) * (8 * 64) + (t & 63);
#pragma unroll
        for (int i = 0; i < 8; i++)
            outA4[base + i * 64] = A4[base + i * 64];
        return;
    }
    __shared__ float WT[64 * 64];  // WT[ci][co]
    __shared__ float bs[64];
    int n = blockIdx.x, tid = threadIdx.x;
    int p = blockIdx.y * 256 + tid;  // t*256+v index
    for (int i = tid; i < 4096; i += 256) WT[(i & 63) * 64 + (i >> 6)] = Wc[i];
    if (tid < 64) bs[tid] = bc[tid];
    __syncthreads();

    float acc[64];
#pragma unroll
    for (int c = 0; c < 64; c++) acc[c] = bs[c];
#pragma unroll 4
    for (int ci = 0; ci < 64; ci++) {
        float xv = x[((size_t)n * 64 + ci) * 4096 + p];
        const float4* wr = (const float4*)&WT[ci * 64];
#pragma unroll
        for (int q = 0; q < 16; q++) {
            float4 w4 = wr[q];
            acc[q * 4 + 0] = fmaf(w4.x, xv, acc[q * 4 + 0]);
            acc[q * 4 + 1] = fmaf(w4.y, xv, acc[q * 4 + 1]);
            acc[q * 4 + 2] = fmaf(w4.z, xv, acc[q * 4 + 2]);
            acc[q * 4 + 3] = fmaf(w4.w, xv, acc[q * 4 + 3]);
        }
    }
#pragma unroll
    for (int c = 0; c < 64; c++)
        xcb[((size_t)n * 64 + c) * 4096 + p] = __float2bfloat16(acc[c]);
}

// ---------------------------------------------------------------------------
// K3 fused v7: producer/consumer wave specialization with SPLIT loops.
//  waves 0-3 (producers): Phase A only, setprio(1), h1 weights pre-selected
//    per lane (bit-identical math, halves h1 FMA count).
//  waves 4-7 (consumers): staging + Phase B; acc[16] only on this path.
//  Barrier counts identical on both paths (1 zero + 1 prologue + 16 loop + 1 dls).
// LDS layout identical to verified round-6.
#define H1SZ 2048
#define H2RS 72
#define HWAVE (H1SZ + 64 * H2RS)            // 6656
#define LDS_H0 16
#define LDS_MS (LDS_H0 + 4 * HWAVE)         // 26640
#define MSBUF (64 * 32 * 16)                // 32768
#define LDS_XS (LDS_MS + 2 * MSBUF)         // 92176
#define XSBUF 32768
#define LDS_TOTAL (LDS_XS + 2 * XSBUF)      // 157712

__device__ inline int h1_off(int row, int h) {
    int u = row * 2 + h;
    u ^= (row >> 2) & 1;
    return u * 16;
}
__device__ inline int ms_off(int C, int w, int v3) {
    int u = (C << 5) | (((w << 1) | v3) ^ (C & 7));
    return u * 16;
}

__global__ __launch_bounds__(512, 2) void k_fuse(
    const float* __restrict__ A, const float* __restrict__ hm,
    const __hip_bfloat16* __restrict__ xcb,
    const float* __restrict__ nh_w1, const float* __restrict__ nh_b1,
    const float* __restrict__ nh_w2, const float* __restrict__ nh_b2,
    const float* __restrict__ nh_w3, const float* __restrict__ nh_b3,
    const float* __restrict__ h_w1, const float* __restrict__ h_b1,
    const float* __restrict__ h_w2, const float* __restrict__ h_b2,
    const float* __restrict__ h_w3, const float* __restrict__ h_b3,
    float* __restrict__ out)
{
    __shared__ char smem[LDS_TOTAL];
    int tid = threadIdx.x, lane = tid & 63, wid = tid >> 6;  // wid 0..7
    int n = blockIdx.x, wt = blockIdx.y;
    int col = lane & 15, quad = lane >> 4;
    bool is_prod = (wid < 4);
    int pwid = wid & 3;

    char* h1b = smem + LDS_H0 + pwid * HWAVE;
    char* h2b = h1b + H1SZ;
    float* dls = (float*)(smem + LDS_H0);  // reused after h regions are dead

    if (tid < 4) ((unsigned*)smem)[tid] = 0;  // shared 16B zero block
    __syncthreads();  // (1) zero block visible

    if (is_prod) {
        // ================= PRODUCER PATH =================
        int w_lane = wt * 16 + pwid * 4 + quad;
        bool flag_lane = hm[n * 256 + w_lane] > 0.5f;
        bool fg[4];
#pragma unroll
        for (int g = 0; g < 4; g++)
            fg[g] = hm[n * 256 + wt * 16 + pwid * 4 + g] > 0.5f;

        // h1 weights pre-selected per lane (flag fixed per lane; bit-identical)
        float w1s[80], b1s[16];
#pragma unroll
        for (int i = 0; i < 80; i++) w1s[i] = flag_lane ? h_w1[i] : nh_w1[i];
#pragma unroll
        for (int o = 0; o < 16; o++) b1s[o] = flag_lane ? h_b1[o] : nh_b1[o];

        U16B w2u_n[2], w2u_h[2], w3u_n[4], w3u_h[4];
        f32x4 b2f_n[2], b2f_h[2];
        float b3c_n[4], b3c_h[4];
#pragma unroll
        for (int ot = 0; ot < 2; ot++) {
#pragma unroll
            for (int j = 0; j < 8; j++) {
                int k = quad * 8 + j;
                w2u_n[ot].us[j] = (k < 16) ? f2bf(nh_w2[(ot * 16 + col) * 16 + k]) : (unsigned short)0;
                w2u_h[ot].us[j] = (k < 16) ? f2bf(h_w2[(ot * 16 + col) * 16 + k]) : (unsigned short)0;
            }
#pragma unroll
            for (int r = 0; r < 4; r++) {
                b2f_n[ot][r] = nh_b2[ot * 16 + quad * 4 + r];
                b2f_h[ot][r] = h_b2[ot * 16 + quad * 4 + r];
            }
        }
#pragma unroll
        for (int ot = 0; ot < 4; ot++) {
#pragma unroll
            for (int j = 0; j < 8; j++) {
                w3u_n[ot].us[j] = f2bf(nh_w3[(ot * 16 + col) * 32 + quad * 8 + j]);
                w3u_h[ot].us[j] = f2bf(h_w3[(ot * 16 + col) * 32 + quad * 8 + j]);
            }
            b3c_n[ot] = nh_b3[ot * 16 + col];
            b3c_h[ot] = h_b3[ot * 16 + col];
        }

        float asum = 0.f;
        float a_cur[5];
#pragma unroll
        for (int k = 0; k < 5; k++)
            a_cur[k] = A[(((size_t)n * 5 + k) * 256 + col) * 256 + w_lane];

        auto phaseA = [&](int vcc) {
            char* msb = smem + LDS_MS + (vcc & 1) * MSBUF;
            float a[5];
#pragma unroll
            for (int k = 0; k < 5; k++) { a[k] = a_cur[k]; asum += a[k]; }

            if (vcc < 15) {
                int v = (vcc + 1) * 16 + col;
#pragma unroll
                for (int k = 0; k < 5; k++)
                    a_cur[k] = A[(((size_t)n * 5 + k) * 256 + v) * 256 + w_lane];
            }

            float h1s[16];
#pragma unroll
            for (int o = 0; o < 16; o++) {
                float s = b1s[o];
#pragma unroll
                for (int k = 0; k < 5; k++)
                    s = fmaf(w1s[o * 5 + k], a[k], s);
                h1s[o] = fmaxf(s, 0.f);
            }
            uint4 q0, q1;
            q0.x = cvtpk(h1s[0], h1s[1]);   q0.y = cvtpk(h1s[2], h1s[3]);
            q0.z = cvtpk(h1s[4], h1s[5]);   q0.w = cvtpk(h1s[6], h1s[7]);
            q1.x = cvtpk(h1s[8], h1s[9]);   q1.y = cvtpk(h1s[10], h1s[11]);
            q1.z = cvtpk(h1s[12], h1s[13]); q1.w = cvtpk(h1s[14], h1s[15]);
            *(uint4*)(h1b + h1_off(lane, 0)) = q0;
            *(uint4*)(h1b + h1_off(lane, 1)) = q1;

#pragma unroll
            for (int pt = 0; pt < 4; pt++) {
                int row = pt * 16 + col;
                U16B af1;
                {
                    const char* p1 = (quad < 2) ? (h1b + h1_off(row, quad)) : smem;
                    af1.u4 = *(const uint4*)p1;
                }
                auto body = [&](const U16B (&w2u)[2], const f32x4 (&b2f)[2],
                                const U16B (&w3u)[4], const float (&b3c)[4]) {
                    f32x4 a0 = b2f[0], a1 = b2f[1];
                    a0 = __builtin_amdgcn_mfma_f32_16x16x32_bf16(af1.s8, w2u[0].s8, a0, 0, 0, 0);
                    a1 = __builtin_amdgcn_mfma_f32_16x16x32_bf16(af1.s8, w2u[1].s8, a1, 0, 0, 0);
                    uint2 pk;
                    pk.x = cvtpk(fmaxf(a0[0], 0.f), fmaxf(a0[1], 0.f));
                    pk.y = cvtpk(fmaxf(a0[2], 0.f), fmaxf(a0[3], 0.f));
                    *(uint2*)(h2b + row * H2RS + quad * 8) = pk;
                    pk.x = cvtpk(fmaxf(a1[0], 0.f), fmaxf(a1[1], 0.f));
                    pk.y = cvtpk(fmaxf(a1[2], 0.f), fmaxf(a1[3], 0.f));
                    *(uint2*)(h2b + row * H2RS + 32 + quad * 8) = pk;
                    U16B af2;
                    af2.u2[0] = *(const uint2*)(h2b + row * H2RS + quad * 16);
                    af2.u2[1] = *(const uint2*)(h2b + row * H2RS + quad * 16 + 8);
#pragma unroll
                    for (int ot = 0; ot < 4; ot++) {
                        f32x4 a3 = f32x4{b3c[ot], b3c[ot], b3c[ot], b3c[ot]};
                        a3 = __builtin_amdgcn_mfma_f32_16x16x32_bf16(w3u[ot].s8, af2.s8, a3, 0, 0, 0);
                        uint2 mv;
                        mv.x = cvtpk(fmaxf(a3[0], 0.f), fmaxf(a3[1], 0.f));
                        mv.y = cvtpk(fmaxf(a3[2], 0.f), fmaxf(a3[3], 0.f));
                        *(uint2*)(msb + ms_off(ot * 16 + col, pwid * 4 + pt, quad >> 1) +
                                  (quad & 1) * 8) = mv;
                    }
                };
                if (fg[pt]) body(w2u_h, b2f_h, w3u_h, b3c_h);
                else        body(w2u_n, b2f_n, w3u_n, b3c_n);
            }
        };

        __builtin_amdgcn_s_setprio(1);
        phaseA(0);
        __syncthreads();  // (2) prologue
        for (int k = 0; k < 16; k++) {
            if (k < 15) phaseA(k + 1);
            __syncthreads();  // (3..18) loop barriers
        }
        __builtin_amdgcn_s_setprio(0);

        // degree norm: reduce asum over the 16 col-lanes (same w per group)
        float s = asum;
        s += __shfl_xor(s, 1);
        s += __shfl_xor(s, 2);
        s += __shfl_xor(s, 4);
        s += __shfl_xor(s, 8);
        if (col == 0) dls[pwid * 4 + quad] = 1.f / (s + 0.001f);
        __syncthreads();  // (19) dls published
    } else {
        // ================= CONSUMER PATH =================
        int st_subcl = lane >> 5, st_vh = (lane >> 4) & 1, st_t = lane & 15;
        const short* st_base = (const short*)xcb +
            (((size_t)n * 64 + pwid * 16 + st_subcl) * 16 + st_t) * 256 + st_vh * 8;

        f32x4 acc[16];
#pragma unroll
        for (int i = 0; i < 16; i++) acc[i] = f32x4{0.f, 0.f, 0.f, 0.f};

        auto stage = [&](int vcc) {
            char* xsb_w = smem + LDS_XS + (vcc & 1) * XSBUF + pwid * 8192;
            const short* g0 = st_base + vcc * 16;
#pragma unroll
            for (int clp = 0; clp < 8; clp++) {
                __builtin_amdgcn_global_load_lds(
                    (const __attribute__((address_space(1))) unsigned*)(g0 + (size_t)clp * 2 * 4096),
                    (__attribute__((address_space(3))) unsigned*)(xsb_w + clp * 1024),
                    16, 0, 0);
            }
        };
        auto phaseB = [&](int vcc) {
            const char* msb = smem + LDS_MS + (vcc & 1) * MSBUF;
            const char* xsb_r = smem + LDS_XS + (vcc & 1) * XSBUF + pwid * 8192;
#pragma unroll
            for (int cl = 0; cl < 16; cl++) {
                int c = pwid * 16 + cl;
                U16B af;
                af.u4 = *(const uint4*)(xsb_r + (cl >> 1) * 1024 +
                                        (((cl & 1) * 32 + (quad & 1) * 16 + col) * 16));
                const char* bp = (quad < 2)
                    ? (const char*)(msb + ms_off(c, col, quad))
                    : (const char*)smem;  // zero block nulls k>=16
                U16B bf; bf.u4 = *(const uint4*)bp;
                acc[cl] = __builtin_amdgcn_mfma_f32_16x16x32_bf16(af.s8, bf.s8, acc[cl], 0, 0, 0);
            }
        };

        stage(0);
        __syncthreads();  // (2) prologue
        for (int k = 0; k < 16; k++) {
            if (k < 15) stage(k + 1);
            phaseB(k);
            __syncthreads();  // (3..18) loop barriers
        }
        __syncthreads();  // (19) dls published by producers

        float dlw = dls[col];
#pragma unroll
        for (int cl = 0; cl < 16; cl++) {
            int c = pwid * 16 + cl;
#pragma unroll
            for (int r = 0; r < 4; r++)
                out[(((size_t)n * 64 + c) * 16 + quad * 4 + r) * 256 + wt * 16 + col] =
                    acc[cl][r] * dlw;
        }
    }
}

// ---------------------------------------------------------------------------
extern "C" void kernel_launch(void* const* d_in, const int* in_sizes, int n_in,
                              void* d_out, int out_size, void* d_ws, size_t ws_size,
                              hipStream_t stream)
{
    const float* x      = (const float*)d_in[0];
    const float* A      = (const float*)d_in[1];
    const float* hmask  = (const float*)d_in[2];
    const float* conv_w = (const float*)d_in[4];
    const float* conv_b = (const float*)d_in[5];
    const float* nh_w1 = (const float*)d_in[6];
    const float* nh_b1 = (const float*)d_in[7];
    const float* nh_w2 = (const float*)d_in[8];
    const float* nh_b2 = (const float*)d_in[9];
    const float* nh_w3 = (const float*)d_in[10];
    const float* nh_b3 = (const float*)d_in[11];
    const float* h_w1 = (const float*)d_in[12];
    const float* h_b1 = (const float*)d_in[13];
    const float* h_w2 = (const float*)d_in[14];
    const float* h_b2 = (const float*)d_in[15];
    const float* h_w3 = (const float*)d_in[16];
    const float* h_b3 = (const float*)d_in[17];

    float* out  = (float*)d_out;
    float* outA = out + (size_t)NB * CC * TT * VV;

    __hip_bfloat16* xcb = (__hip_bfloat16*)d_ws;  // 16.8 MB

    k_pre<<<dim3(NB, 56), 256, 0, stream>>>(x, conv_w, conv_b, xcb,
                                            (const float4*)A, (float4*)outA);
    k_fuse<<<dim3(NB, 16), 512, 0, stream>>>(
        A, hmask, xcb,
        nh_w1, nh_b1, nh_w2, nh_b2, nh_w3, nh_b3,
        h_w1, h_b1, h_w2, h_b2, h_w3, h_b3, out);
}